// Round 1
// baseline (4269.477 us; speedup 1.0000x reference)
//
#include <hip/hip_runtime.h>
#include <math.h>

#define NROWS 16384
#define DIMK  1024
#define MDIC  4096
#define KSEL  16

// ---- output layout (f32 elements, concatenated in reference return order) ----
#define OFF_RECON   0
#define OFF_RESID   ((size_t)NROWS*DIMK)                  // 16777216
#define OFF_CHOSEN  ((size_t)2*NROWS*DIMK)                // 33554432
#define OFF_WEIGHTS (OFF_CHOSEN + 16)                     // 33554448
#define OFF_WT      (OFF_WEIGHTS + 16)                    // 33554464
#define OFF_EVR     (OFF_WT + (size_t)NROWS*KSEL)         // 33816608
#define OFF_L2      (OFF_EVR + 16)
#define OFF_COS     (OFF_L2 + 16)

// ------------------------------- helpers -------------------------------------
__device__ inline float blockReduce256f(float v) {
    __shared__ float ws_[4];
    #pragma unroll
    for (int off = 32; off > 0; off >>= 1) v += __shfl_down(v, off);
    __syncthreads();
    if ((threadIdx.x & 63) == 0) ws_[threadIdx.x >> 6] = v;
    __syncthreads();
    return ws_[0] + ws_[1] + ws_[2] + ws_[3];
}

__device__ inline double blockReduceD(double v) {
    __shared__ double sred[4];
    #pragma unroll
    for (int off = 32; off > 0; off >>= 1) v += __shfl_down(v, off);
    __syncthreads();
    if ((threadIdx.x & 63) == 0) sred[threadIdx.x >> 6] = v;
    __syncthreads();
    return sred[0] + sred[1] + sred[2] + sred[3];
}

// ------------------------------- kernels -------------------------------------
__global__ void k_init(float* notchosen) {
    int m = blockIdx.x * 256 + threadIdx.x;
    if (m < MDIC) notchosen[m] = 1.0f;
}

// column sums (for mean) + total sum of squares; partials, deterministic
__global__ __launch_bounds__(256) void k_colstats(const float* __restrict__ X,
                                                  float* __restrict__ colpart,
                                                  float* __restrict__ sqpart) {
    int d  = blockIdx.x * 256 + threadIdx.x;
    int r0 = blockIdx.y * 256;
    float s = 0.f, sq = 0.f;
    for (int r = 0; r < 256; ++r) {
        float v = X[(size_t)(r0 + r) * DIMK + d];
        s += v; sq += v * v;
    }
    colpart[(size_t)blockIdx.y * DIMK + d] = s;
    __shared__ float red[256];
    red[threadIdx.x] = sq; __syncthreads();
    for (int off = 128; off > 0; off >>= 1) {
        if (threadIdx.x < off) red[threadIdx.x] += red[threadIdx.x + off];
        __syncthreads();
    }
    if (threadIdx.x == 0) sqpart[blockIdx.y * 4 + blockIdx.x] = red[0];
}

// xmean[d]; scal[0]=sumX2, scal[1]=sumXc2, scal[2]=||xmean||^2
__global__ __launch_bounds__(1024) void k_reduce_mean(const float* __restrict__ colpart,
                                                      const float* __restrict__ sqpart,
                                                      float* __restrict__ xmean,
                                                      double* __restrict__ scal) {
    int d = threadIdx.x;
    double s = 0.0;
    for (int y = 0; y < 64; ++y) s += (double)colpart[(size_t)y * DIMK + d];
    float m = (float)(s / (double)NROWS);
    xmean[d] = m;
    __shared__ double red[1024];
    red[d] = (double)m * (double)m; __syncthreads();
    for (int off = 512; off > 0; off >>= 1) {
        if (d < off) red[d] += red[d + off];
        __syncthreads();
    }
    if (d == 0) {
        double xmn2 = red[0];
        double sx2 = 0.0;
        for (int i = 0; i < 256; ++i) sx2 += (double)sqpart[i];
        scal[0] = sx2;
        scal[1] = sx2 - (double)NROWS * xmn2;   // sum of squares of centered X
        scal[2] = xmn2;
    }
}

// md[m] = xmean . Dict[m]
__global__ __launch_bounds__(256) void k_md(const float* __restrict__ Dict,
                                            const float* __restrict__ xmean,
                                            float* __restrict__ md) {
    int m = blockIdx.x, t = threadIdx.x;
    float4 a = ((const float4*)(Dict + (size_t)m * DIMK))[t];
    float4 b = ((const float4*)xmean)[t];
    float s = a.x * b.x + a.y * b.y + a.z * b.z + a.w * b.w;
    s = blockReduce256f(s);
    if (t == 0) md[m] = s;
}

// per-row ||X_n||^2 and X_n . xmean
__global__ __launch_bounds__(256) void k_rowstats(const float* __restrict__ X,
                                                  const float* __restrict__ xmean,
                                                  float* __restrict__ Xnorm2,
                                                  float* __restrict__ XdotM) {
    int n = blockIdx.x, t = threadIdx.x;
    float4 x = ((const float4*)(X + (size_t)n * DIMK))[t];
    float4 m = ((const float4*)xmean)[t];
    float s2 = x.x * x.x + x.y * x.y + x.z * x.z + x.w * x.w;
    float sm = x.x * m.x + x.y * m.y + x.z * m.z + x.w * m.w;
    s2 = blockReduce256f(s2);
    sm = blockReduce256f(sm);
    if (t == 0) { Xnorm2[n] = s2; XdotM[n] = sm; }
}

// C0[n,m] = X_n . D_m - md[m]   (= centered-X . D_m)
// 128x128 tile, BK=16, 256 threads, 8x8 per thread
__global__ __launch_bounds__(256) void k_gemm(const float* __restrict__ X,
                                              const float* __restrict__ Dict,
                                              const float* __restrict__ md,
                                              float* __restrict__ C0) {
    __shared__ float As[16][128];
    __shared__ float Bs[16][128];
    int tid = threadIdx.x;
    int tx = tid & 15, ty = tid >> 4;
    int rowA0 = blockIdx.y * 128;   // rows of X
    int rowB0 = blockIdx.x * 128;   // dict atoms
    int lr = tid >> 2, lk = (tid & 3) << 2;
    const float* Ap = X    + (size_t)(rowA0 + lr) * DIMK + lk;
    const float* Bp = Dict + (size_t)(rowB0 + lr) * DIMK + lk;
    float acc[8][8];
    #pragma unroll
    for (int i = 0; i < 8; ++i)
        #pragma unroll
        for (int j = 0; j < 8; ++j) acc[i][j] = 0.f;

    for (int k0 = 0; k0 < DIMK; k0 += 16) {
        float4 a0 = *(const float4*)Ap;
        float4 a1 = *(const float4*)(Ap + (size_t)64 * DIMK);
        float4 b0 = *(const float4*)Bp;
        float4 b1 = *(const float4*)(Bp + (size_t)64 * DIMK);
        __syncthreads();
        As[lk + 0][lr] = a0.x; As[lk + 1][lr] = a0.y; As[lk + 2][lr] = a0.z; As[lk + 3][lr] = a0.w;
        As[lk + 0][lr + 64] = a1.x; As[lk + 1][lr + 64] = a1.y; As[lk + 2][lr + 64] = a1.z; As[lk + 3][lr + 64] = a1.w;
        Bs[lk + 0][lr] = b0.x; Bs[lk + 1][lr] = b0.y; Bs[lk + 2][lr] = b0.z; Bs[lk + 3][lr] = b0.w;
        Bs[lk + 0][lr + 64] = b1.x; Bs[lk + 1][lr + 64] = b1.y; Bs[lk + 2][lr + 64] = b1.z; Bs[lk + 3][lr + 64] = b1.w;
        __syncthreads();
        #pragma unroll
        for (int kk = 0; kk < 16; ++kk) {
            float4 av0 = *(const float4*)&As[kk][ty * 4];
            float4 av1 = *(const float4*)&As[kk][ty * 4 + 64];
            float4 bv0 = *(const float4*)&Bs[kk][tx * 4];
            float4 bv1 = *(const float4*)&Bs[kk][tx * 4 + 64];
            float ar[8] = {av0.x, av0.y, av0.z, av0.w, av1.x, av1.y, av1.z, av1.w};
            float br[8] = {bv0.x, bv0.y, bv0.z, bv0.w, bv1.x, bv1.y, bv1.z, bv1.w};
            #pragma unroll
            for (int i = 0; i < 8; ++i)
                #pragma unroll
                for (int j = 0; j < 8; ++j)
                    acc[i][j] += ar[i] * br[j];
        }
        Ap += 16; Bp += 16;
    }
    float4 mda = *(const float4*)&md[rowB0 + tx * 4];
    float4 mdb = *(const float4*)&md[rowB0 + tx * 4 + 64];
    #pragma unroll
    for (int i = 0; i < 8; ++i) {
        int r = rowA0 + ((i < 4) ? (ty * 4 + i) : (64 + ty * 4 + i - 4));
        float* cp = C0 + (size_t)r * MDIC + rowB0;
        float4 o0 = {acc[i][0] - mda.x, acc[i][1] - mda.y, acc[i][2] - mda.z, acc[i][3] - mda.w};
        float4 o1 = {acc[i][4] - mdb.x, acc[i][5] - mdb.y, acc[i][6] - mdb.z, acc[i][7] - mdb.w};
        *(float4*)(cp + tx * 4) = o0;
        *(float4*)(cp + tx * 4 + 64) = o1;
    }
}

// scores partials: sum_n |C0[n,m] - sum_j W[j,n]*GR[j,m]| over an n-chunk
// grid (8, 32), block 256; each thread owns m and m+256
template <int NA>
__global__ __launch_bounds__(256) void k_score(const float* __restrict__ C0,
                                               const float* __restrict__ GR,
                                               const float* __restrict__ Wm,
                                               double* __restrict__ scoreP) {
    __shared__ float Wl[KSEL > 0 ? KSEL : 1][128];
    int tid = threadIdx.x;
    int m0 = blockIdx.x * 512 + tid;
    int m1 = m0 + 256;
    float gr0[NA > 0 ? NA : 1], gr1[NA > 0 ? NA : 1];
    #pragma unroll
    for (int j = 0; j < NA; ++j) {
        gr0[j] = GR[(size_t)j * MDIC + m0];
        gr1[j] = GR[(size_t)j * MDIC + m1];
    }
    double acc0 = 0.0, acc1 = 0.0;
    int nbase = blockIdx.y * 512;
    for (int c = 0; c < 4; ++c) {
        int n0 = nbase + c * 128;
        __syncthreads();
        for (int idx = tid; idx < NA * 128; idx += 256) {
            int j = idx >> 7, nn = idx & 127;
            Wl[j][nn] = Wm[(size_t)j * NROWS + n0 + nn];
        }
        __syncthreads();
        float f0 = 0.f, f1 = 0.f;
        for (int nn = 0; nn < 128; ++nn) {
            size_t base = (size_t)(n0 + nn) * MDIC;
            float v0 = C0[base + m0], v1 = C0[base + m1];
            float cr0 = 0.f, cr1 = 0.f;
            #pragma unroll
            for (int j = 0; j < NA; ++j) {
                float wv = Wl[j][nn];
                cr0 += wv * gr0[j];
                cr1 += wv * gr1[j];
            }
            f0 += fabsf(v0 - cr0);
            f1 += fabsf(v1 - cr1);
        }
        acc0 += (double)f0; acc1 += (double)f1;
    }
    scoreP[(size_t)blockIdx.y * MDIC + m0] = acc0;
    scoreP[(size_t)blockIdx.y * MDIC + m1] = acc1;
}

// reduce partials, mask, argmax (first-max tie-break), select atom
__global__ __launch_bounds__(1024) void k_argmax(const double* __restrict__ scoreP,
                                                 float* __restrict__ notchosen,
                                                 int* __restrict__ chosen,
                                                 float* __restrict__ outChosen,
                                                 int iter) {
    int t = threadIdx.x;
    double best = -1e300; int bidx = 0;
    for (int q = 0; q < 4; ++q) {
        int m = q * 1024 + t;
        double s = 0.0;
        for (int y = 0; y < 32; ++y) s += scoreP[(size_t)y * MDIC + m];
        if (notchosen[m] == 0.f) s = -1.0;   // scores are >= 0; excluded
        if (s > best) { best = s; bidx = m; }
    }
    __shared__ double sv[1024];
    __shared__ int    si[1024];
    sv[t] = best; si[t] = bidx; __syncthreads();
    for (int off = 512; off > 0; off >>= 1) {
        if (t < off) {
            double ov = sv[t + off]; int oi = si[t + off];
            if (ov > sv[t] || (ov == sv[t] && oi < si[t])) { sv[t] = ov; si[t] = oi; }
        }
        __syncthreads();
    }
    if (t == 0) {
        int c = si[0];
        chosen[iter] = c;
        notchosen[c] = 0.f;
        outChosen[iter] = (float)c;
    }
}

// GR[iter][m] = atom_c . D_m
__global__ __launch_bounds__(256) void k_gramrow(const float* __restrict__ Dict,
                                                 const int* __restrict__ chosen,
                                                 float* __restrict__ GR, int iter) {
    int m = blockIdx.x, t = threadIdx.x;
    int c = chosen[iter];
    float4 a = ((const float4*)(Dict + (size_t)c * DIMK))[t];
    float4 b = ((const float4*)(Dict + (size_t)m * DIMK))[t];
    float s = a.x * b.x + a.y * b.y + a.z * b.z + a.w * b.w;
    s = blockReduce256f(s);
    if (t == 0) GR[(size_t)iter * MDIC + m] = s;
}

// build G_cc from GR gathers, Cholesky (serial, tiny), gather mdot
__global__ __launch_bounds__(256) void k_chol(const float* __restrict__ GR,
                                              const float* __restrict__ mdv,
                                              const int* __restrict__ chosen,
                                              float* __restrict__ Lmat,
                                              float* __restrict__ Gcc,
                                              float* __restrict__ mdot, int nat) {
    __shared__ float G[16][16];
    __shared__ float L[16][16];
    int t = threadIdx.x;
    if (t < nat * nat) {
        int a = t / nat, b = t % nat;
        G[a][b] = GR[(size_t)a * MDIC + chosen[b]];
    }
    if (t < nat) mdot[t] = mdv[chosen[t]];
    __syncthreads();
    if (t == 0) {
        for (int a = 0; a < nat; ++a)
            for (int b = 0; b <= a; ++b) {
                float s = G[a][b];
                for (int x = 0; x < b; ++x) s -= L[a][x] * L[b][x];
                L[a][b] = (a == b) ? sqrtf(fmaxf(s, 1e-20f)) : s / L[b][b];
            }
    }
    __syncthreads();
    if (t < nat * nat) {
        int a = t / nat, b = t % nat;
        Gcc[a * 16 + b]  = G[a][b];
        Lmat[a * 16 + b] = (b <= a) ? L[a][b] : 0.f;
    }
}

// per-row Cholesky solve: W = (L L^T)^{-1} B,  B[j,n] = C0[n, c_j]
template <int NAT>
__global__ __launch_bounds__(256) void k_solve(const float* __restrict__ C0,
                                               const float* __restrict__ Lmat,
                                               const int* __restrict__ chosen,
                                               float* __restrict__ Wm,
                                               float* __restrict__ Bm) {
    __shared__ float L[16][16];
    __shared__ int cI[16];
    int t = threadIdx.x;
    if (t < NAT * NAT) L[t / NAT][t % NAT] = Lmat[(t / NAT) * 16 + (t % NAT)];
    if (t < NAT) cI[t] = chosen[t];
    __syncthreads();
    int n = blockIdx.x * 256 + t;
    float b[NAT], y[NAT], w[NAT];
    #pragma unroll
    for (int j = 0; j < NAT; ++j) b[j] = C0[(size_t)n * MDIC + cI[j]];
    #pragma unroll
    for (int a = 0; a < NAT; ++a) {
        float s = b[a];
        #pragma unroll
        for (int x = 0; x < NAT; ++x) if (x < a) s -= L[a][x] * y[x];
        y[a] = s / L[a][a];
    }
    #pragma unroll
    for (int a = NAT - 1; a >= 0; --a) {
        float s = y[a];
        #pragma unroll
        for (int x = 0; x < NAT; ++x) if (x > a) s -= L[x][a] * w[x];
        w[a] = s / L[a][a];
    }
    #pragma unroll
    for (int j = 0; j < NAT; ++j) {
        Wm[(size_t)j * NROWS + n] = w[j];
        Bm[(size_t)j * NROWS + n] = b[j];
    }
}

// per-row metric contributions, block partials
template <int NAT>
__global__ __launch_bounds__(256) void k_stats(const float* __restrict__ Wm,
                                               const float* __restrict__ Bm,
                                               const float* __restrict__ Gcc,
                                               const float* __restrict__ mdot,
                                               const float* __restrict__ Xnorm2,
                                               const float* __restrict__ XdotM,
                                               const double* __restrict__ scal,
                                               double* __restrict__ statsP) {
    __shared__ float G[16][16];
    __shared__ float mdl[16];
    int t = threadIdx.x;
    if (t < NAT * NAT) G[t / NAT][t % NAT] = Gcc[(t / NAT) * 16 + (t % NAT)];
    if (t < NAT) mdl[t] = mdot[t];
    __syncthreads();
    int n = blockIdx.x * 256 + t;
    float w[NAT], bb[NAT];
    #pragma unroll
    for (int j = 0; j < NAT; ++j) {
        w[j]  = Wm[(size_t)j * NROWS + n];
        bb[j] = Bm[(size_t)j * NROWS + n];
    }
    float q = 0.f, wb = 0.f, wmd = 0.f, num1 = 0.f;
    #pragma unroll
    for (int j = 0; j < NAT; ++j) {
        float gw = 0.f;
        #pragma unroll
        for (int x = 0; x < NAT; ++x) gw += G[j][x] * w[x];
        q    += w[j] * gw;
        wb   += w[j] * bb[j];
        wmd  += w[j] * mdl[j];
        num1 += w[j] * (bb[j] + mdl[j]);
    }
    float xmn2 = (float)scal[2];
    float rec2 = xmn2 + 2.f * wmd + q;
    float na = fmaxf(sqrtf(Xnorm2[n]), 1e-8f);
    float nb = fmaxf(sqrtf(fmaxf(rec2, 0.f)), 1e-8f);
    float cosn = (XdotM[n] + num1) / (na * nb);

    double r0 = blockReduceD((double)q);
    double r1 = blockReduceD((double)wb);
    double r2 = blockReduceD((double)cosn);
    if (t == 0) {
        statsP[(size_t)blockIdx.x * 40 + 0] = r0;
        statsP[(size_t)blockIdx.x * 40 + 1] = r1;
        statsP[(size_t)blockIdx.x * 40 + 2] = r2;
    }
    for (int j = 0; j < NAT; ++j) {
        double rw = blockReduceD((double)w[j]);
        double rq = blockReduceD((double)w[j] * (double)w[j]);
        if (t == 0) {
            statsP[(size_t)blockIdx.x * 40 + 3 + j]  = rw;
            statsP[(size_t)blockIdx.x * 40 + 19 + j] = rq;
        }
    }
}

// single wave: combine 64 block partials -> evr/l2/cos (+weights on last iter)
template <int NAT>
__global__ __launch_bounds__(64) void k_finalize(const double* __restrict__ statsP,
                                                 const float* __restrict__ Gcc,
                                                 const double* __restrict__ scal,
                                                 float* __restrict__ out, int iter) {
    int t = threadIdx.x;  // 0..63, one per stats block
    double q  = statsP[(size_t)t * 40 + 0];
    double wb = statsP[(size_t)t * 40 + 1];
    double cs = statsP[(size_t)t * 40 + 2];
    double ws[NAT], wq[NAT];
    #pragma unroll
    for (int j = 0; j < NAT; ++j) {
        ws[j] = statsP[(size_t)t * 40 + 3 + j];
        wq[j] = statsP[(size_t)t * 40 + 19 + j];
    }
    #pragma unroll
    for (int off = 32; off > 0; off >>= 1) {
        q  += __shfl_down(q, off);
        wb += __shfl_down(wb, off);
        cs += __shfl_down(cs, off);
        #pragma unroll
        for (int j = 0; j < NAT; ++j) {
            ws[j] += __shfl_down(ws[j], off);
            wq[j] += __shfl_down(wq[j], off);
        }
    }
    double wbar[NAT];
    #pragma unroll
    for (int j = 0; j < NAT; ++j) wbar[j] = __shfl(ws[j], 0) / (double)NROWS;
    double wg = 0.0;
    for (int idx = t; idx < NAT * NAT; idx += 64) {
        int a = idx / NAT, b = idx % NAT;
        wg += wbar[a] * wbar[b] * (double)Gcc[a * 16 + b];
    }
    #pragma unroll
    for (int off = 32; off > 0; off >>= 1) wg += __shfl_down(wg, off);
    if (t == 0) {
        double sumXc2 = scal[1];
        out[OFF_EVR + iter] = (float)((q - (double)NROWS * wg) / sumXc2);
        out[OFF_L2  + iter] = (float)((sumXc2 - 2.0 * wb + q) / ((double)NROWS * (double)DIMK));
        out[OFF_COS + iter] = (float)(cs / (double)NROWS);
        if (NAT == KSEL) {
            for (int j = 0; j < NAT; ++j)
                out[OFF_WEIGHTS + j] = (float)sqrt(wq[j]);
        }
    }
}

// final recon / residual outputs
__global__ __launch_bounds__(256) void k_outfinal(const float* __restrict__ X,
                                                  const float* __restrict__ xmean,
                                                  const float* __restrict__ Dict,
                                                  const int* __restrict__ chosen,
                                                  const float* __restrict__ Wm,
                                                  float* __restrict__ out) {
    __shared__ int cI[16];
    int t = threadIdx.x;
    if (t < 16) cI[t] = chosen[t];
    __syncthreads();
    int n0 = blockIdx.x * 8;
    float4 xm = ((const float4*)xmean)[t];
    for (int r = 0; r < 8; ++r) {
        int n = n0 + r;
        float w[16];
        #pragma unroll
        for (int j = 0; j < 16; ++j) w[j] = Wm[(size_t)j * NROWS + n];
        float4 rec = xm;
        #pragma unroll
        for (int j = 0; j < 16; ++j) {
            float4 a = ((const float4*)(Dict + (size_t)cI[j] * DIMK))[t];
            rec.x += w[j] * a.x; rec.y += w[j] * a.y;
            rec.z += w[j] * a.z; rec.w += w[j] * a.w;
        }
        float4 xv = ((const float4*)(X + (size_t)n * DIMK))[t];
        float4 res = {xv.x - rec.x, xv.y - rec.y, xv.z - rec.z, xv.w - rec.w};
        ((float4*)(out + OFF_RECON + (size_t)n * DIMK))[t] = rec;
        ((float4*)(out + OFF_RESID + (size_t)n * DIMK))[t] = res;
    }
}

__global__ __launch_bounds__(256) void k_wt(const float* __restrict__ Wm,
                                            float* __restrict__ out) {
    int idx = blockIdx.x * 256 + threadIdx.x;  // n*16 + j
    int n = idx >> 4, j = idx & 15;
    out[OFF_WT + idx] = Wm[(size_t)j * NROWS + n];
}

// ------------------------------ host side ------------------------------------
struct IterArgs {
    const float *X, *Dict;
    float *C0, *GR, *W, *Bm, *md, *xmean, *Xnorm2, *XdotM, *notchosen, *Lmat, *Gcc, *mdot;
    double *scoreP, *scal, *statsP;
    int *chosen;
    float *out;
    hipStream_t stream;
};

template <int I>
static void run_iter(const IterArgs& a) {
    k_score<I><<<dim3(8, 32), 256, 0, a.stream>>>(a.C0, a.GR, a.W, a.scoreP);
    k_argmax<<<1, 1024, 0, a.stream>>>(a.scoreP, a.notchosen, a.chosen, a.out + OFF_CHOSEN, I);
    k_gramrow<<<MDIC, 256, 0, a.stream>>>(a.Dict, a.chosen, a.GR, I);
    k_chol<<<1, 256, 0, a.stream>>>(a.GR, a.md, a.chosen, a.Lmat, a.Gcc, a.mdot, I + 1);
    k_solve<I + 1><<<64, 256, 0, a.stream>>>(a.C0, a.Lmat, a.chosen, a.W, a.Bm);
    k_stats<I + 1><<<64, 256, 0, a.stream>>>(a.W, a.Bm, a.Gcc, a.mdot, a.Xnorm2, a.XdotM, a.scal, a.statsP);
    k_finalize<I + 1><<<1, 64, 0, a.stream>>>(a.statsP, a.Gcc, a.scal, a.out, I);
}

template <int I>
struct Loop {
    static void go(const IterArgs& a) { run_iter<I>(a); Loop<I + 1>::go(a); }
};
template <>
struct Loop<KSEL> { static void go(const IterArgs&) {} };

extern "C" void kernel_launch(void* const* d_in, const int* in_sizes, int n_in,
                              void* d_out, int out_size, void* d_ws, size_t ws_size,
                              hipStream_t stream) {
    (void)in_sizes; (void)n_in; (void)out_size; (void)ws_size;
    const float* X    = (const float*)d_in[0];
    const float* Dict = (const float*)d_in[1];
    float* out = (float*)d_out;

    char* ws = (char*)d_ws;
    size_t off = 0;
    auto carve = [&](size_t bytes) -> char* {
        char* p = ws + off;
        off += (bytes + 255) & ~(size_t)255;
        return p;
    };
    float*  C0        = (float*) carve((size_t)NROWS * MDIC * 4);   // 268 MB
    float*  GR        = (float*) carve((size_t)KSEL * MDIC * 4);
    float*  W         = (float*) carve((size_t)KSEL * NROWS * 4);
    float*  Bm        = (float*) carve((size_t)KSEL * NROWS * 4);
    float*  md        = (float*) carve((size_t)MDIC * 4);
    float*  xmean     = (float*) carve((size_t)DIMK * 4);
    float*  colpart   = (float*) carve((size_t)64 * DIMK * 4);
    float*  sqpart    = (float*) carve(256 * 4);
    float*  Xnorm2    = (float*) carve((size_t)NROWS * 4);
    float*  XdotM     = (float*) carve((size_t)NROWS * 4);
    double* scoreP    = (double*)carve((size_t)32 * MDIC * 8);
    float*  notchosen = (float*) carve((size_t)MDIC * 4);
    int*    chosen    = (int*)   carve(KSEL * 4);
    float*  Lmat      = (float*) carve(256 * 4);
    float*  Gcc       = (float*) carve(256 * 4);
    float*  mdot      = (float*) carve(16 * 4);
    double* scal      = (double*)carve(8 * 8);
    double* statsP    = (double*)carve((size_t)64 * 40 * 8);

    k_init<<<MDIC / 256, 256, 0, stream>>>(notchosen);
    k_colstats<<<dim3(4, 64), 256, 0, stream>>>(X, colpart, sqpart);
    k_reduce_mean<<<1, 1024, 0, stream>>>(colpart, sqpart, xmean, scal);
    k_md<<<MDIC, 256, 0, stream>>>(Dict, xmean, md);
    k_rowstats<<<NROWS, 256, 0, stream>>>(X, xmean, Xnorm2, XdotM);
    k_gemm<<<dim3(MDIC / 128, NROWS / 128), 256, 0, stream>>>(X, Dict, md, C0);

    IterArgs a{X, Dict, C0, GR, W, Bm, md, xmean, Xnorm2, XdotM, notchosen,
               Lmat, Gcc, mdot, scoreP, scal, statsP, chosen, out, stream};
    Loop<0>::go(a);

    k_outfinal<<<NROWS / 8, 256, 0, stream>>>(X, xmean, Dict, chosen, W, out);
    k_wt<<<NROWS * KSEL / 256, 256, 0, stream>>>(W, out);
}

// Round 2
// 2232.135 us; speedup vs baseline: 1.9127x; 1.9127x over previous
//
#include <hip/hip_runtime.h>
#include <math.h>

#define NROWS 16384
#define DIMK  1024
#define MDIC  4096
#define KSEL  16

// ---- output layout (f32 elements, concatenated in reference return order) ----
#define OFF_RECON   0
#define OFF_RESID   ((size_t)NROWS*DIMK)                  // 16777216
#define OFF_CHOSEN  ((size_t)2*NROWS*DIMK)                // 33554432
#define OFF_WEIGHTS (OFF_CHOSEN + 16)                     // 33554448
#define OFF_WT      (OFF_WEIGHTS + 16)                    // 33554464
#define OFF_EVR     (OFF_WT + (size_t)NROWS*KSEL)         // 33816608
#define OFF_L2      (OFF_EVR + 16)
#define OFF_COS     (OFF_L2 + 16)

typedef unsigned short u16;
typedef __attribute__((ext_vector_type(8))) short short8;   // 8 bf16 (4 VGPRs)
typedef __attribute__((ext_vector_type(4))) float f32x4;

// ------------------------------- helpers -------------------------------------
__device__ inline float blockReduce256f(float v) {
    __shared__ float ws_[4];
    #pragma unroll
    for (int off = 32; off > 0; off >>= 1) v += __shfl_down(v, off);
    __syncthreads();
    if ((threadIdx.x & 63) == 0) ws_[threadIdx.x >> 6] = v;
    __syncthreads();
    return ws_[0] + ws_[1] + ws_[2] + ws_[3];
}

__device__ inline double blockReduceD(double v) {
    __shared__ double sred[4];
    #pragma unroll
    for (int off = 32; off > 0; off >>= 1) v += __shfl_down(v, off);
    __syncthreads();
    if ((threadIdx.x & 63) == 0) sred[threadIdx.x >> 6] = v;
    __syncthreads();
    return sred[0] + sred[1] + sred[2] + sred[3];
}

__device__ inline u16 f2bf(float f) {
    unsigned u = __float_as_uint(f);
    unsigned r = u + 0x7FFFu + ((u >> 16) & 1u);   // round-to-nearest-even
    return (u16)(r >> 16);
}
__device__ inline float bf2f(u16 h) { return __uint_as_float(((unsigned)h) << 16); }

// ------------------------------- kernels -------------------------------------
__global__ void k_init(float* notchosen) {
    int m = blockIdx.x * 256 + threadIdx.x;
    if (m < MDIC) notchosen[m] = 1.0f;
}

// column sums (for mean) + total sum of squares; partials, deterministic
__global__ __launch_bounds__(256) void k_colstats(const float* __restrict__ X,
                                                  float* __restrict__ colpart,
                                                  float* __restrict__ sqpart) {
    int d  = blockIdx.x * 256 + threadIdx.x;
    int r0 = blockIdx.y * 256;
    float s = 0.f, sq = 0.f;
    for (int r = 0; r < 256; ++r) {
        float v = X[(size_t)(r0 + r) * DIMK + d];
        s += v; sq += v * v;
    }
    colpart[(size_t)blockIdx.y * DIMK + d] = s;
    __shared__ float red[256];
    red[threadIdx.x] = sq; __syncthreads();
    for (int off = 128; off > 0; off >>= 1) {
        if (threadIdx.x < off) red[threadIdx.x] += red[threadIdx.x + off];
        __syncthreads();
    }
    if (threadIdx.x == 0) sqpart[blockIdx.y * 4 + blockIdx.x] = red[0];
}

// xmean[d]; scal[0]=sumX2, scal[1]=sumXc2, scal[2]=||xmean||^2
__global__ __launch_bounds__(1024) void k_reduce_mean(const float* __restrict__ colpart,
                                                      const float* __restrict__ sqpart,
                                                      float* __restrict__ xmean,
                                                      double* __restrict__ scal) {
    int d = threadIdx.x;
    double s = 0.0;
    for (int y = 0; y < 64; ++y) s += (double)colpart[(size_t)y * DIMK + d];
    float m = (float)(s / (double)NROWS);
    xmean[d] = m;
    __shared__ double red[1024];
    red[d] = (double)m * (double)m; __syncthreads();
    for (int off = 512; off > 0; off >>= 1) {
        if (d < off) red[d] += red[d + off];
        __syncthreads();
    }
    if (d == 0) {
        double xmn2 = red[0];
        double sx2 = 0.0;
        for (int i = 0; i < 256; ++i) sx2 += (double)sqpart[i];
        scal[0] = sx2;
        scal[1] = sx2 - (double)NROWS * xmn2;   // sum of squares of centered X
        scal[2] = xmn2;
    }
}

// md[m] = xmean . Dict[m]
__global__ __launch_bounds__(256) void k_md(const float* __restrict__ Dict,
                                            const float* __restrict__ xmean,
                                            float* __restrict__ md) {
    int m = blockIdx.x, t = threadIdx.x;
    float4 a = ((const float4*)(Dict + (size_t)m * DIMK))[t];
    float4 b = ((const float4*)xmean)[t];
    float s = a.x * b.x + a.y * b.y + a.z * b.z + a.w * b.w;
    s = blockReduce256f(s);
    if (t == 0) md[m] = s;
}

// per-row ||X_n||^2 and X_n . xmean
__global__ __launch_bounds__(256) void k_rowstats(const float* __restrict__ X,
                                                  const float* __restrict__ xmean,
                                                  float* __restrict__ Xnorm2,
                                                  float* __restrict__ XdotM) {
    int n = blockIdx.x, t = threadIdx.x;
    float4 x = ((const float4*)(X + (size_t)n * DIMK))[t];
    float4 m = ((const float4*)xmean)[t];
    float s2 = x.x * x.x + x.y * x.y + x.z * x.z + x.w * x.w;
    float sm = x.x * m.x + x.y * m.y + x.z * m.z + x.w * m.w;
    s2 = blockReduce256f(s2);
    sm = blockReduce256f(sm);
    if (t == 0) { Xnorm2[n] = s2; XdotM[n] = sm; }
}

// split f32 -> bf16 hi + bf16 lo planes (row-major, K=1024 contiguous)
__global__ __launch_bounds__(256) void k_split(const float* __restrict__ src,
                                               u16* __restrict__ hi,
                                               u16* __restrict__ lo) {
    size_t idx = ((size_t)blockIdx.x * 256 + threadIdx.x) * 4;
    float4 v = *(const float4*)(src + idx);
    ushort4 h, l;
    h.x = f2bf(v.x); l.x = f2bf(v.x - bf2f(h.x));
    h.y = f2bf(v.y); l.y = f2bf(v.y - bf2f(h.y));
    h.z = f2bf(v.z); l.z = f2bf(v.z - bf2f(h.z));
    h.w = f2bf(v.w); l.w = f2bf(v.w - bf2f(h.w));
    *(ushort4*)(hi + idx) = h;
    *(ushort4*)(lo + idx) = l;
}

// bf16x3 MFMA GEMM: C0[n,m] = X_n . D_m - md[m]
// 128x128 tile, BK=32, 256 threads (4 waves, each 64x64 = 4x4 frags of 16x16x32)
// global_load_lds width=16 staging; wave w stages plane w (Ahi/Alo/Bhi/Blo)
__global__ __launch_bounds__(256) void k_gemm_mfma(const u16* __restrict__ Ahi,
                                                   const u16* __restrict__ Alo,
                                                   const u16* __restrict__ Bhi,
                                                   const u16* __restrict__ Blo,
                                                   const float* __restrict__ md,
                                                   float* __restrict__ C0,
                                                   int rowAbase) {
    __shared__ u16 sAh[128 * 32];
    __shared__ u16 sAl[128 * 32];
    __shared__ u16 sBh[128 * 32];
    __shared__ u16 sBl[128 * 32];
    int tid  = threadIdx.x;
    int wave = tid >> 6, lane = tid & 63;
    int rowA0 = blockIdx.y * 128;    // within chunk
    int rowB0 = blockIdx.x * 128;

    const u16* gsrc = (wave == 0) ? Ahi : (wave == 1) ? Alo : (wave == 2) ? Bhi : Blo;
    u16* sdst       = (wave == 0) ? sAh : (wave == 1) ? sAl : (wave == 2) ? sBh : sBl;
    int grow0 = (wave < 2) ? rowA0 : rowB0;
    // lane -> row lane/4, 16B-chunk lane%4 within a 64B row of the k-slab
    const u16* gbase = gsrc + (size_t)(grow0 + (lane >> 2)) * DIMK + ((lane & 3) << 3);

    f32x4 zero = {0.f, 0.f, 0.f, 0.f};
    f32x4 acc[4][4];
    #pragma unroll
    for (int i = 0; i < 4; ++i)
        #pragma unroll
        for (int j = 0; j < 4; ++j) acc[i][j] = zero;

    int lm = lane & 15, lk = lane >> 4;
    int wi = wave >> 1, wj = wave & 1;

    for (int k0 = 0; k0 < DIMK; k0 += 32) {
        __syncthreads();
        #pragma unroll
        for (int i = 0; i < 8; ++i) {
            __builtin_amdgcn_global_load_lds(
                (__attribute__((address_space(1))) void*)(gbase + k0 + (size_t)i * 16 * DIMK),
                (__attribute__((address_space(3))) void*)(sdst + i * 512),
                16, 0, 0);
        }
        __syncthreads();
        short8 ah[4], al[4], bh[4], bl[4];
        #pragma unroll
        for (int f = 0; f < 4; ++f) {
            int ra = (wi * 64 + f * 16 + lm) * 32 + lk * 8;
            ah[f] = *(const short8*)&sAh[ra];
            al[f] = *(const short8*)&sAl[ra];
            int rb = (wj * 64 + f * 16 + lm) * 32 + lk * 8;
            bh[f] = *(const short8*)&sBh[rb];
            bl[f] = *(const short8*)&sBl[rb];
        }
        #pragma unroll
        for (int fi = 0; fi < 4; ++fi)
            #pragma unroll
            for (int fj = 0; fj < 4; ++fj) {
                acc[fi][fj] = __builtin_amdgcn_mfma_f32_16x16x32_bf16(ah[fi], bh[fj], acc[fi][fj], 0, 0, 0);
                acc[fi][fj] = __builtin_amdgcn_mfma_f32_16x16x32_bf16(ah[fi], bl[fj], acc[fi][fj], 0, 0, 0);
                acc[fi][fj] = __builtin_amdgcn_mfma_f32_16x16x32_bf16(al[fi], bh[fj], acc[fi][fj], 0, 0, 0);
            }
    }
    // C/D layout: col = lane&15 (B/n-operand -> m), row = (lane>>4)*4 + reg (A -> n)
    #pragma unroll
    for (int fj = 0; fj < 4; ++fj) {
        int m = rowB0 + wj * 64 + fj * 16 + lm;
        float mdv = md[m];
        #pragma unroll
        for (int fi = 0; fi < 4; ++fi) {
            int nb = rowAbase + rowA0 + wi * 64 + fi * 16 + lk * 4;
            #pragma unroll
            for (int r = 0; r < 4; ++r)
                C0[(size_t)(nb + r) * MDIC + m] = acc[fi][fj][r] - mdv;
        }
    }
}

// score partials: sum_n |C0[n,m] - sum_j W[j,n]*GR[j,m]| over 64-row chunk
// grid (4, 256), block 256; thread owns 4 consecutive m (float4 loads)
template <int NA>
__global__ __launch_bounds__(256) void k_score(const float* __restrict__ C0,
                                               const float* __restrict__ GR,
                                               const float* __restrict__ Wm,
                                               float* __restrict__ scorePf) {
    constexpr int NAX = NA ? NA : 1;
    __shared__ float Wl[NAX][64];
    int t = threadIdx.x;
    int m0 = blockIdx.x * 1024 + t * 4;
    int n0 = blockIdx.y * 64;
    float4 gr[NAX];
    #pragma unroll
    for (int j = 0; j < NA; ++j) gr[j] = *(const float4*)&GR[(size_t)j * MDIC + m0];
    for (int idx = t; idx < NA * 64; idx += 256) {
        int j = idx >> 6, nn = idx & 63;
        Wl[j][nn] = Wm[(size_t)j * NROWS + n0 + nn];
    }
    __syncthreads();
    float4 acc = {0.f, 0.f, 0.f, 0.f};
    for (int nn = 0; nn < 64; ++nn) {
        float4 c = *(const float4*)&C0[(size_t)(n0 + nn) * MDIC + m0];
        float4 cr = {0.f, 0.f, 0.f, 0.f};
        #pragma unroll
        for (int j = 0; j < NA; ++j) {
            float wv = Wl[j][nn];
            cr.x += wv * gr[j].x; cr.y += wv * gr[j].y;
            cr.z += wv * gr[j].z; cr.w += wv * gr[j].w;
        }
        acc.x += fabsf(c.x - cr.x); acc.y += fabsf(c.y - cr.y);
        acc.z += fabsf(c.z - cr.z); acc.w += fabsf(c.w - cr.w);
    }
    *(float4*)&scorePf[(size_t)blockIdx.y * MDIC + m0] = acc;
}

// deterministic double reduction of 256 fp32 partials per m
__global__ __launch_bounds__(256) void k_scorered(const float* __restrict__ scorePf,
                                                  double* __restrict__ score) {
    int m = blockIdx.x * 256 + threadIdx.x;
    double s = 0.0;
    for (int y = 0; y < 256; ++y) s += (double)scorePf[(size_t)y * MDIC + m];
    score[m] = s;
}

// mask + argmax (first-max tie-break), select atom
__global__ __launch_bounds__(1024) void k_argmax(const double* __restrict__ score,
                                                 float* __restrict__ notchosen,
                                                 int* __restrict__ chosen,
                                                 float* __restrict__ outChosen,
                                                 int iter) {
    int t = threadIdx.x;
    double best = -1e300; int bidx = 0;
    for (int q = 0; q < 4; ++q) {
        int m = q * 1024 + t;
        double s = score[m];
        if (notchosen[m] == 0.f) s = -1.0;   // scores are >= 0; excluded
        if (s > best) { best = s; bidx = m; }
    }
    __shared__ double sv[1024];
    __shared__ int    si[1024];
    sv[t] = best; si[t] = bidx; __syncthreads();
    for (int off = 512; off > 0; off >>= 1) {
        if (t < off) {
            double ov = sv[t + off]; int oi = si[t + off];
            if (ov > sv[t] || (ov == sv[t] && oi < si[t])) { sv[t] = ov; si[t] = oi; }
        }
        __syncthreads();
    }
    if (t == 0) {
        int c = si[0];
        chosen[iter] = c;
        notchosen[c] = 0.f;
        outChosen[iter] = (float)c;
    }
}

// GR[iter][m] = atom_c . D_m  (exact fp32)
__global__ __launch_bounds__(256) void k_gramrow(const float* __restrict__ Dict,
                                                 const int* __restrict__ chosen,
                                                 float* __restrict__ GR, int iter) {
    int m = blockIdx.x, t = threadIdx.x;
    int c = chosen[iter];
    float4 a = ((const float4*)(Dict + (size_t)c * DIMK))[t];
    float4 b = ((const float4*)(Dict + (size_t)m * DIMK))[t];
    float s = a.x * b.x + a.y * b.y + a.z * b.z + a.w * b.w;
    s = blockReduce256f(s);
    if (t == 0) GR[(size_t)iter * MDIC + m] = s;
}

// build G_cc from GR gathers, Cholesky (serial, tiny), gather mdot
__global__ __launch_bounds__(256) void k_chol(const float* __restrict__ GR,
                                              const float* __restrict__ mdv,
                                              const int* __restrict__ chosen,
                                              float* __restrict__ Lmat,
                                              float* __restrict__ Gcc,
                                              float* __restrict__ mdot, int nat) {
    __shared__ float G[16][16];
    __shared__ float L[16][16];
    int t = threadIdx.x;
    if (t < nat * nat) {
        int a = t / nat, b = t % nat;
        G[a][b] = GR[(size_t)a * MDIC + chosen[b]];
    }
    if (t < nat) mdot[t] = mdv[chosen[t]];
    __syncthreads();
    if (t == 0) {
        for (int a = 0; a < nat; ++a)
            for (int b = 0; b <= a; ++b) {
                float s = G[a][b];
                for (int x = 0; x < b; ++x) s -= L[a][x] * L[b][x];
                L[a][b] = (a == b) ? sqrtf(fmaxf(s, 1e-20f)) : s / L[b][b];
            }
    }
    __syncthreads();
    if (t < nat * nat) {
        int a = t / nat, b = t % nat;
        Gcc[a * 16 + b]  = G[a][b];
        Lmat[a * 16 + b] = (b <= a) ? L[a][b] : 0.f;
    }
}

// per-row Cholesky solve: W = (L L^T)^{-1} B,  B[j,n] = C0[n, c_j]
template <int NAT>
__global__ __launch_bounds__(256) void k_solve(const float* __restrict__ C0,
                                               const float* __restrict__ Lmat,
                                               const int* __restrict__ chosen,
                                               float* __restrict__ Wm,
                                               float* __restrict__ Bm) {
    __shared__ float L[16][16];
    __shared__ int cI[16];
    int t = threadIdx.x;
    if (t < NAT * NAT) L[t / NAT][t % NAT] = Lmat[(t / NAT) * 16 + (t % NAT)];
    if (t < NAT) cI[t] = chosen[t];
    __syncthreads();
    int n = blockIdx.x * 256 + t;
    float b[NAT], y[NAT], w[NAT];
    #pragma unroll
    for (int j = 0; j < NAT; ++j) b[j] = C0[(size_t)n * MDIC + cI[j]];
    #pragma unroll
    for (int a = 0; a < NAT; ++a) {
        float s = b[a];
        #pragma unroll
        for (int x = 0; x < NAT; ++x) if (x < a) s -= L[a][x] * y[x];
        y[a] = s / L[a][a];
    }
    #pragma unroll
    for (int a = NAT - 1; a >= 0; --a) {
        float s = y[a];
        #pragma unroll
        for (int x = 0; x < NAT; ++x) if (x > a) s -= L[x][a] * w[x];
        w[a] = s / L[a][a];
    }
    #pragma unroll
    for (int j = 0; j < NAT; ++j) {
        Wm[(size_t)j * NROWS + n] = w[j];
        Bm[(size_t)j * NROWS + n] = b[j];
    }
}

// per-row metric contributions, block partials
template <int NAT>
__global__ __launch_bounds__(256) void k_stats(const float* __restrict__ Wm,
                                               const float* __restrict__ Bm,
                                               const float* __restrict__ Gcc,
                                               const float* __restrict__ mdot,
                                               const float* __restrict__ Xnorm2,
                                               const float* __restrict__ XdotM,
                                               const double* __restrict__ scal,
                                               double* __restrict__ statsP) {
    __shared__ float G[16][16];
    __shared__ float mdl[16];
    int t = threadIdx.x;
    if (t < NAT * NAT) G[t / NAT][t % NAT] = Gcc[(t / NAT) * 16 + (t % NAT)];
    if (t < NAT) mdl[t] = mdot[t];
    __syncthreads();
    int n = blockIdx.x * 256 + t;
    float w[NAT], bb[NAT];
    #pragma unroll
    for (int j = 0; j < NAT; ++j) {
        w[j]  = Wm[(size_t)j * NROWS + n];
        bb[j] = Bm[(size_t)j * NROWS + n];
    }
    float q = 0.f, wb = 0.f, wmd = 0.f, num1 = 0.f;
    #pragma unroll
    for (int j = 0; j < NAT; ++j) {
        float gw = 0.f;
        #pragma unroll
        for (int x = 0; x < NAT; ++x) gw += G[j][x] * w[x];
        q    += w[j] * gw;
        wb   += w[j] * bb[j];
        wmd  += w[j] * mdl[j];
        num1 += w[j] * (bb[j] + mdl[j]);
    }
    float xmn2 = (float)scal[2];
    float rec2 = xmn2 + 2.f * wmd + q;
    float na = fmaxf(sqrtf(Xnorm2[n]), 1e-8f);
    float nb = fmaxf(sqrtf(fmaxf(rec2, 0.f)), 1e-8f);
    float cosn = (XdotM[n] + num1) / (na * nb);

    double r0 = blockReduceD((double)q);
    double r1 = blockReduceD((double)wb);
    double r2 = blockReduceD((double)cosn);
    if (t == 0) {
        statsP[(size_t)blockIdx.x * 40 + 0] = r0;
        statsP[(size_t)blockIdx.x * 40 + 1] = r1;
        statsP[(size_t)blockIdx.x * 40 + 2] = r2;
    }
    for (int j = 0; j < NAT; ++j) {
        double rw = blockReduceD((double)w[j]);
        double rq = blockReduceD((double)w[j] * (double)w[j]);
        if (t == 0) {
            statsP[(size_t)blockIdx.x * 40 + 3 + j]  = rw;
            statsP[(size_t)blockIdx.x * 40 + 19 + j] = rq;
        }
    }
}

// single wave: combine 64 block partials -> evr/l2/cos (+weights on last iter)
template <int NAT>
__global__ __launch_bounds__(64) void k_finalize(const double* __restrict__ statsP,
                                                 const float* __restrict__ Gcc,
                                                 const double* __restrict__ scal,
                                                 float* __restrict__ out, int iter) {
    int t = threadIdx.x;  // 0..63, one per stats block
    double q  = statsP[(size_t)t * 40 + 0];
    double wb = statsP[(size_t)t * 40 + 1];
    double cs = statsP[(size_t)t * 40 + 2];
    double ws[NAT], wq[NAT];
    #pragma unroll
    for (int j = 0; j < NAT; ++j) {
        ws[j] = statsP[(size_t)t * 40 + 3 + j];
        wq[j] = statsP[(size_t)t * 40 + 19 + j];
    }
    #pragma unroll
    for (int off = 32; off > 0; off >>= 1) {
        q  += __shfl_down(q, off);
        wb += __shfl_down(wb, off);
        cs += __shfl_down(cs, off);
        #pragma unroll
        for (int j = 0; j < NAT; ++j) {
            ws[j] += __shfl_down(ws[j], off);
            wq[j] += __shfl_down(wq[j], off);
        }
    }
    double wbar[NAT];
    #pragma unroll
    for (int j = 0; j < NAT; ++j) wbar[j] = __shfl(ws[j], 0) / (double)NROWS;
    double wg = 0.0;
    for (int idx = t; idx < NAT * NAT; idx += 64) {
        int a = idx / NAT, b = idx % NAT;
        wg += wbar[a] * wbar[b] * (double)Gcc[a * 16 + b];
    }
    #pragma unroll
    for (int off = 32; off > 0; off >>= 1) wg += __shfl_down(wg, off);
    if (t == 0) {
        double sumXc2 = scal[1];
        out[OFF_EVR + iter] = (float)((q - (double)NROWS * wg) / sumXc2);
        out[OFF_L2  + iter] = (float)((sumXc2 - 2.0 * wb + q) / ((double)NROWS * (double)DIMK));
        out[OFF_COS + iter] = (float)(cs / (double)NROWS);
        if (NAT == KSEL) {
            for (int j = 0; j < NAT; ++j)
                out[OFF_WEIGHTS + j] = (float)sqrt(wq[j]);
        }
    }
}

// final recon / residual outputs
__global__ __launch_bounds__(256) void k_outfinal(const float* __restrict__ X,
                                                  const float* __restrict__ xmean,
                                                  const float* __restrict__ Dict,
                                                  const int* __restrict__ chosen,
                                                  const float* __restrict__ Wm,
                                                  float* __restrict__ out) {
    __shared__ int cI[16];
    int t = threadIdx.x;
    if (t < 16) cI[t] = chosen[t];
    __syncthreads();
    int n0 = blockIdx.x * 8;
    float4 xm = ((const float4*)xmean)[t];
    for (int r = 0; r < 8; ++r) {
        int n = n0 + r;
        float w[16];
        #pragma unroll
        for (int j = 0; j < 16; ++j) w[j] = Wm[(size_t)j * NROWS + n];
        float4 rec = xm;
        #pragma unroll
        for (int j = 0; j < 16; ++j) {
            float4 a = ((const float4*)(Dict + (size_t)cI[j] * DIMK))[t];
            rec.x += w[j] * a.x; rec.y += w[j] * a.y;
            rec.z += w[j] * a.z; rec.w += w[j] * a.w;
        }
        float4 xv = ((const float4*)(X + (size_t)n * DIMK))[t];
        float4 res = {xv.x - rec.x, xv.y - rec.y, xv.z - rec.z, xv.w - rec.w};
        ((float4*)(out + OFF_RECON + (size_t)n * DIMK))[t] = rec;
        ((float4*)(out + OFF_RESID + (size_t)n * DIMK))[t] = res;
    }
}

__global__ __launch_bounds__(256) void k_wt(const float* __restrict__ Wm,
                                            float* __restrict__ out) {
    int idx = blockIdx.x * 256 + threadIdx.x;  // n*16 + j
    int n = idx >> 4, j = idx & 15;
    out[OFF_WT + idx] = Wm[(size_t)j * NROWS + n];
}

// ------------------------------ host side ------------------------------------
struct IterArgs {
    const float *X, *Dict;
    float *C0, *GR, *W, *Bm, *md, *xmean, *Xnorm2, *XdotM, *notchosen, *Lmat, *Gcc, *mdot;
    float *scorePf;
    double *score, *scal, *statsP;
    int *chosen;
    float *out;
    hipStream_t stream;
};

template <int I>
static void run_iter(const IterArgs& a) {
    k_score<I><<<dim3(4, 256), 256, 0, a.stream>>>(a.C0, a.GR, a.W, a.scorePf);
    k_scorered<<<16, 256, 0, a.stream>>>(a.scorePf, a.score);
    k_argmax<<<1, 1024, 0, a.stream>>>(a.score, a.notchosen, a.chosen, a.out + OFF_CHOSEN, I);
    k_gramrow<<<MDIC, 256, 0, a.stream>>>(a.Dict, a.chosen, a.GR, I);
    k_chol<<<1, 256, 0, a.stream>>>(a.GR, a.md, a.chosen, a.Lmat, a.Gcc, a.mdot, I + 1);
    k_solve<I + 1><<<64, 256, 0, a.stream>>>(a.C0, a.Lmat, a.chosen, a.W, a.Bm);
    k_stats<I + 1><<<64, 256, 0, a.stream>>>(a.W, a.Bm, a.Gcc, a.mdot, a.Xnorm2, a.XdotM, a.scal, a.statsP);
    k_finalize<I + 1><<<1, 64, 0, a.stream>>>(a.statsP, a.Gcc, a.scal, a.out, I);
}

template <int I>
struct Loop {
    static void go(const IterArgs& a) { run_iter<I>(a); Loop<I + 1>::go(a); }
};
template <>
struct Loop<KSEL> { static void go(const IterArgs&) {} };

extern "C" void kernel_launch(void* const* d_in, const int* in_sizes, int n_in,
                              void* d_out, int out_size, void* d_ws, size_t ws_size,
                              hipStream_t stream) {
    (void)in_sizes; (void)n_in; (void)out_size;
    const float* X    = (const float*)d_in[0];
    const float* Dict = (const float*)d_in[1];
    float* out = (float*)d_out;

    char* ws = (char*)d_ws;
    size_t off = 0;
    auto carve = [&](size_t bytes) -> char* {
        char* p = ws + off;
        off += (bytes + 255) & ~(size_t)255;
        return p;
    };
    float*  C0        = (float*) carve((size_t)NROWS * MDIC * 4);   // 268 MB
    float*  GR        = (float*) carve((size_t)KSEL * MDIC * 4);
    float*  W         = (float*) carve((size_t)KSEL * NROWS * 4);
    float*  Bm        = (float*) carve((size_t)KSEL * NROWS * 4);
    float*  md        = (float*) carve((size_t)MDIC * 4);
    float*  xmean     = (float*) carve((size_t)DIMK * 4);
    float*  colpart   = (float*) carve((size_t)64 * DIMK * 4);
    float*  sqpart    = (float*) carve(256 * 4);
    float*  Xnorm2    = (float*) carve((size_t)NROWS * 4);
    float*  XdotM     = (float*) carve((size_t)NROWS * 4);
    float*  scorePf   = (float*) carve((size_t)256 * MDIC * 4);     // 4 MB
    double* score     = (double*)carve((size_t)MDIC * 8);
    float*  notchosen = (float*) carve((size_t)MDIC * 4);
    int*    chosen    = (int*)   carve(KSEL * 4);
    float*  Lmat      = (float*) carve(256 * 4);
    float*  Gcc       = (float*) carve(256 * 4);
    float*  mdot      = (float*) carve(16 * 4);
    double* scal      = (double*)carve(8 * 8);
    double* statsP    = (double*)carve((size_t)64 * 40 * 8);
    u16*    Bhi       = (u16*)   carve((size_t)MDIC * DIMK * 2);    // 8 MB
    u16*    Blo       = (u16*)   carve((size_t)MDIC * DIMK * 2);    // 8 MB

    // A-plane chunk buffers take the tail of ws; pick largest chunk that fits.
    int chunkrows = 0;
    for (int cr = NROWS; cr >= 128; cr >>= 1) {
        size_t need = (size_t)cr * DIMK * 2 * 2 + 512;
        if (off + need <= ws_size) { chunkrows = cr; break; }
    }
    if (chunkrows == 0) chunkrows = 128;  // last resort (ws too small would be fatal anyway)
    u16* Ahi = (u16*) carve((size_t)chunkrows * DIMK * 2);
    u16* Alo = (u16*) carve((size_t)chunkrows * DIMK * 2);

    k_init<<<MDIC / 256, 256, 0, stream>>>(notchosen);
    k_colstats<<<dim3(4, 64), 256, 0, stream>>>(X, colpart, sqpart);
    k_reduce_mean<<<1, 1024, 0, stream>>>(colpart, sqpart, xmean, scal);
    k_md<<<MDIC, 256, 0, stream>>>(Dict, xmean, md);
    k_rowstats<<<NROWS, 256, 0, stream>>>(X, xmean, Xnorm2, XdotM);

    // bf16 hi/lo planes + chunked MFMA GEMM
    k_split<<<(MDIC * DIMK) / 1024, 256, 0, stream>>>(Dict, Bhi, Blo);
    int nchunks = NROWS / chunkrows;
    for (int c = 0; c < nchunks; ++c) {
        k_split<<<(chunkrows * DIMK) / 1024, 256, 0, stream>>>(
            X + (size_t)c * chunkrows * DIMK, Ahi, Alo);
        k_gemm_mfma<<<dim3(MDIC / 128, chunkrows / 128), 256, 0, stream>>>(
            Ahi, Alo, Bhi, Blo, md, C0, c * chunkrows);
    }

    IterArgs a{X, Dict, C0, GR, W, Bm, md, xmean, Xnorm2, XdotM, notchosen,
               Lmat, Gcc, mdot, scorePf, score, scal, statsP, chosen, out, stream};
    Loop<0>::go(a);

    k_outfinal<<<NROWS / 8, 256, 0, stream>>>(X, xmean, Dict, chosen, W, out);
    k_wt<<<NROWS * KSEL / 256, 256, 0, stream>>>(W, out);
}

// Round 3
// 2025.324 us; speedup vs baseline: 2.1080x; 1.1021x over previous
//
#include <hip/hip_runtime.h>
#include <math.h>

#define NROWS 16384
#define DIMK  1024
#define MDIC  4096
#define KSEL  16

// ---- output layout (f32 elements, concatenated in reference return order) ----
#define OFF_RECON   0
#define OFF_RESID   ((size_t)NROWS*DIMK)                  // 16777216
#define OFF_CHOSEN  ((size_t)2*NROWS*DIMK)                // 33554432
#define OFF_WEIGHTS (OFF_CHOSEN + 16)                     // 33554448
#define OFF_WT      (OFF_WEIGHTS + 16)                    // 33554464
#define OFF_EVR     (OFF_WT + (size_t)NROWS*KSEL)         // 33816608
#define OFF_L2      (OFF_EVR + 16)
#define OFF_COS     (OFF_L2 + 16)

typedef unsigned short u16;
typedef unsigned long long u64;
typedef __attribute__((ext_vector_type(8))) short short8;   // 8 bf16 (4 VGPRs)
typedef __attribute__((ext_vector_type(4))) float f32x4;

// ------------------------------- helpers -------------------------------------
__device__ inline float blockReduce256f(float v) {
    __shared__ float ws_[4];
    #pragma unroll
    for (int off = 32; off > 0; off >>= 1) v += __shfl_down(v, off);
    __syncthreads();
    if ((threadIdx.x & 63) == 0) ws_[threadIdx.x >> 6] = v;
    __syncthreads();
    return ws_[0] + ws_[1] + ws_[2] + ws_[3];
}

__device__ inline double blockReduceD(double v) {
    __shared__ double sred[4];
    #pragma unroll
    for (int off = 32; off > 0; off >>= 1) v += __shfl_down(v, off);
    __syncthreads();
    if ((threadIdx.x & 63) == 0) sred[threadIdx.x >> 6] = v;
    __syncthreads();
    return sred[0] + sred[1] + sred[2] + sred[3];
}

__device__ inline u16 f2bf(float f) {
    unsigned u = __float_as_uint(f);
    unsigned r = u + 0x7FFFu + ((u >> 16) & 1u);   // round-to-nearest-even
    return (u16)(r >> 16);
}
__device__ inline float bf2f(u16 h) { return __uint_as_float(((unsigned)h) << 16); }

// ------------------------------- kernels -------------------------------------
__global__ void k_init(float* notchosen, u64* amx) {
    int m = blockIdx.x * 256 + threadIdx.x;
    if (m < MDIC) notchosen[m] = 1.0f;
    if (blockIdx.x == 0 && threadIdx.x < 2) amx[threadIdx.x] = 0ULL;
}

// column sums (for mean) + total sum of squares; partials, deterministic
__global__ __launch_bounds__(256) void k_colstats(const float* __restrict__ X,
                                                  float* __restrict__ colpart,
                                                  float* __restrict__ sqpart) {
    int d  = blockIdx.x * 256 + threadIdx.x;
    int r0 = blockIdx.y * 256;
    float s = 0.f, sq = 0.f;
    for (int r = 0; r < 256; ++r) {
        float v = X[(size_t)(r0 + r) * DIMK + d];
        s += v; sq += v * v;
    }
    colpart[(size_t)blockIdx.y * DIMK + d] = s;
    __shared__ float red[256];
    red[threadIdx.x] = sq; __syncthreads();
    for (int off = 128; off > 0; off >>= 1) {
        if (threadIdx.x < off) red[threadIdx.x] += red[threadIdx.x + off];
        __syncthreads();
    }
    if (threadIdx.x == 0) sqpart[blockIdx.y * 4 + blockIdx.x] = red[0];
}

// xmean[d]; scal[0]=sumX2, scal[1]=sumXc2, scal[2]=||xmean||^2
__global__ __launch_bounds__(1024) void k_reduce_mean(const float* __restrict__ colpart,
                                                      const float* __restrict__ sqpart,
                                                      float* __restrict__ xmean,
                                                      double* __restrict__ scal) {
    int d = threadIdx.x;
    double s = 0.0;
    for (int y = 0; y < 64; ++y) s += (double)colpart[(size_t)y * DIMK + d];
    float m = (float)(s / (double)NROWS);
    xmean[d] = m;
    __shared__ double red[1024];
    red[d] = (double)m * (double)m; __syncthreads();
    for (int off = 512; off > 0; off >>= 1) {
        if (d < off) red[d] += red[d + off];
        __syncthreads();
    }
    if (d == 0) {
        double xmn2 = red[0];
        double sx2 = 0.0;
        for (int i = 0; i < 256; ++i) sx2 += (double)sqpart[i];
        scal[0] = sx2;
        scal[1] = sx2 - (double)NROWS * xmn2;   // sum of squares of centered X
        scal[2] = xmn2;
    }
}

// md[m] = xmean . Dict[m]
__global__ __launch_bounds__(256) void k_md(const float* __restrict__ Dict,
                                            const float* __restrict__ xmean,
                                            float* __restrict__ md) {
    int m = blockIdx.x, t = threadIdx.x;
    float4 a = ((const float4*)(Dict + (size_t)m * DIMK))[t];
    float4 b = ((const float4*)xmean)[t];
    float s = a.x * b.x + a.y * b.y + a.z * b.z + a.w * b.w;
    s = blockReduce256f(s);
    if (t == 0) md[m] = s;
}

// per-row ||X_n||^2 and X_n . xmean
__global__ __launch_bounds__(256) void k_rowstats(const float* __restrict__ X,
                                                  const float* __restrict__ xmean,
                                                  float* __restrict__ Xnorm2,
                                                  float* __restrict__ XdotM) {
    int n = blockIdx.x, t = threadIdx.x;
    float4 x = ((const float4*)(X + (size_t)n * DIMK))[t];
    float4 m = ((const float4*)xmean)[t];
    float s2 = x.x * x.x + x.y * x.y + x.z * x.z + x.w * x.w;
    float sm = x.x * m.x + x.y * m.y + x.z * m.z + x.w * m.w;
    s2 = blockReduce256f(s2);
    sm = blockReduce256f(sm);
    if (t == 0) { Xnorm2[n] = s2; XdotM[n] = sm; }
}

// split f32 -> bf16 hi + bf16 lo planes (row-major, K=1024 contiguous)
__global__ __launch_bounds__(256) void k_split(const float* __restrict__ src,
                                               u16* __restrict__ hi,
                                               u16* __restrict__ lo) {
    size_t idx = ((size_t)blockIdx.x * 256 + threadIdx.x) * 4;
    float4 v = *(const float4*)(src + idx);
    ushort4 h, l;
    h.x = f2bf(v.x); l.x = f2bf(v.x - bf2f(h.x));
    h.y = f2bf(v.y); l.y = f2bf(v.y - bf2f(h.y));
    h.z = f2bf(v.z); l.z = f2bf(v.z - bf2f(h.z));
    h.w = f2bf(v.w); l.w = f2bf(v.w - bf2f(h.w));
    *(ushort4*)(hi + idx) = h;
    *(ushort4*)(lo + idx) = l;
}

// bf16x3 MFMA GEMM -> C0h[n,m] = bf16(X_n . D_m - md[m])
__global__ __launch_bounds__(256) void k_gemm_mfma(const u16* __restrict__ Ahi,
                                                   const u16* __restrict__ Alo,
                                                   const u16* __restrict__ Bhi,
                                                   const u16* __restrict__ Blo,
                                                   const float* __restrict__ md,
                                                   u16* __restrict__ C0h,
                                                   int rowAbase) {
    __shared__ u16 sAh[128 * 32];
    __shared__ u16 sAl[128 * 32];
    __shared__ u16 sBh[128 * 32];
    __shared__ u16 sBl[128 * 32];
    int tid  = threadIdx.x;
    int wave = tid >> 6, lane = tid & 63;
    int rowA0 = blockIdx.y * 128;    // within chunk
    int rowB0 = blockIdx.x * 128;

    const u16* gsrc = (wave == 0) ? Ahi : (wave == 1) ? Alo : (wave == 2) ? Bhi : Blo;
    u16* sdst       = (wave == 0) ? sAh : (wave == 1) ? sAl : (wave == 2) ? sBh : sBl;
    int grow0 = (wave < 2) ? rowA0 : rowB0;
    const u16* gbase = gsrc + (size_t)(grow0 + (lane >> 2)) * DIMK + ((lane & 3) << 3);

    f32x4 zero = {0.f, 0.f, 0.f, 0.f};
    f32x4 acc[4][4];
    #pragma unroll
    for (int i = 0; i < 4; ++i)
        #pragma unroll
        for (int j = 0; j < 4; ++j) acc[i][j] = zero;

    int lm = lane & 15, lk = lane >> 4;
    int wi = wave >> 1, wj = wave & 1;

    for (int k0 = 0; k0 < DIMK; k0 += 32) {
        __syncthreads();
        #pragma unroll
        for (int i = 0; i < 8; ++i) {
            __builtin_amdgcn_global_load_lds(
                (__attribute__((address_space(1))) void*)(gbase + k0 + (size_t)i * 16 * DIMK),
                (__attribute__((address_space(3))) void*)(sdst + i * 512),
                16, 0, 0);
        }
        __syncthreads();
        short8 ah[4], al[4], bh[4], bl[4];
        #pragma unroll
        for (int f = 0; f < 4; ++f) {
            int ra = (wi * 64 + f * 16 + lm) * 32 + lk * 8;
            ah[f] = *(const short8*)&sAh[ra];
            al[f] = *(const short8*)&sAl[ra];
            int rb = (wj * 64 + f * 16 + lm) * 32 + lk * 8;
            bh[f] = *(const short8*)&sBh[rb];
            bl[f] = *(const short8*)&sBl[rb];
        }
        #pragma unroll
        for (int fi = 0; fi < 4; ++fi)
            #pragma unroll
            for (int fj = 0; fj < 4; ++fj) {
                acc[fi][fj] = __builtin_amdgcn_mfma_f32_16x16x32_bf16(ah[fi], bh[fj], acc[fi][fj], 0, 0, 0);
                acc[fi][fj] = __builtin_amdgcn_mfma_f32_16x16x32_bf16(ah[fi], bl[fj], acc[fi][fj], 0, 0, 0);
                acc[fi][fj] = __builtin_amdgcn_mfma_f32_16x16x32_bf16(al[fi], bh[fj], acc[fi][fj], 0, 0, 0);
            }
    }
    // C/D layout: col = lane&15 -> m, row = (lane>>4)*4 + reg -> n
    #pragma unroll
    for (int fj = 0; fj < 4; ++fj) {
        int m = rowB0 + wj * 64 + fj * 16 + lm;
        float mdv = md[m];
        #pragma unroll
        for (int fi = 0; fi < 4; ++fi) {
            int nb = rowAbase + rowA0 + wi * 64 + fi * 16 + lk * 4;
            #pragma unroll
            for (int r = 0; r < 4; ++r)
                C0h[(size_t)(nb + r) * MDIC + m] = f2bf(acc[fi][fj][r] - mdv);
        }
    }
}

// score partials: sum_n |C0h[n,m] - sum_j W[j,n]*GR[j,m]| over 64-row chunk
// grid (4, 256), block 256; thread owns 4 consecutive m
template <int NA>
__global__ __launch_bounds__(256) void k_score(const u16* __restrict__ C0h,
                                               const float* __restrict__ GR,
                                               const float* __restrict__ Wm,
                                               float* __restrict__ scorePf) {
    constexpr int NAX = NA ? NA : 1;
    __shared__ float Wl[NAX][64];
    int t = threadIdx.x;
    int m0 = blockIdx.x * 1024 + t * 4;
    int n0 = blockIdx.y * 64;
    float4 gr[NAX];
    #pragma unroll
    for (int j = 0; j < NA; ++j) gr[j] = *(const float4*)&GR[(size_t)j * MDIC + m0];
    for (int idx = t; idx < NA * 64; idx += 256) {
        int j = idx >> 6, nn = idx & 63;
        Wl[j][nn] = Wm[(size_t)j * NROWS + n0 + nn];
    }
    __syncthreads();
    float4 acc = {0.f, 0.f, 0.f, 0.f};
    for (int nn = 0; nn < 64; ++nn) {
        ushort4 ch = *(const ushort4*)&C0h[(size_t)(n0 + nn) * MDIC + m0];
        float4 c = {bf2f(ch.x), bf2f(ch.y), bf2f(ch.z), bf2f(ch.w)};
        float4 cr = {0.f, 0.f, 0.f, 0.f};
        #pragma unroll
        for (int j = 0; j < NA; ++j) {
            float wv = Wl[j][nn];
            cr.x += wv * gr[j].x; cr.y += wv * gr[j].y;
            cr.z += wv * gr[j].z; cr.w += wv * gr[j].w;
        }
        acc.x += fabsf(c.x - cr.x); acc.y += fabsf(c.y - cr.y);
        acc.z += fabsf(c.z - cr.z); acc.w += fabsf(c.w - cr.w);
    }
    *(float4*)&scorePf[(size_t)blockIdx.y * MDIC + m0] = acc;
}

// fused: reduce partials -> masked argmax via deterministic atomicMax(u64 key),
// last block selects atom, updates notchosen/chosen, resets state.
__global__ __launch_bounds__(256) void k_scoreargmax(const float* __restrict__ scorePf,
                                                     float* __restrict__ notchosen,
                                                     u64* __restrict__ amx,   // [0]=key,[1]=ctr
                                                     int* __restrict__ chosen,
                                                     float* __restrict__ outChosen,
                                                     int iter) {
    int t = threadIdx.x;
    int m = blockIdx.x * 256 + t;
    double s = 0.0;
    for (int y = 0; y < 256; ++y) s += (double)scorePf[(size_t)y * MDIC + m];
    u64 key = 0ULL;
    if (notchosen[m] != 0.f) {
        u64 bits = (u64)__double_as_longlong(s);     // s >= 0: monotone
        key = (bits & ~0xFFFULL) | (u64)(4095 - m);  // ties -> smaller m wins
    }
    __shared__ u64 sk[256];
    sk[t] = key; __syncthreads();
    for (int off = 128; off > 0; off >>= 1) {
        if (t < off) { if (sk[t + off] > sk[t]) sk[t] = sk[t + off]; }
        __syncthreads();
    }
    if (t == 0) {
        atomicMax(&amx[0], sk[0]);
        __threadfence();
        u64 done = atomicAdd(&amx[1], 1ULL);
        if (done == 15ULL) {                         // last of 16 blocks
            u64 k = atomicMax(&amx[0], 0ULL);        // atomic read
            int c = 4095 - (int)(k & 0xFFFULL);
            chosen[iter] = c;
            notchosen[c] = 0.f;
            outChosen[iter] = (float)c;
            amx[0] = 0ULL; amx[1] = 0ULL;            // reset for next iteration
            __threadfence();
        }
    }
}

// fused: GR[iter][m] = atom_c . D_m (blocks 0..4095, exact fp32)
//        Bm[iter][n] = C0h[n, c]    (blocks 4096..4159, new RHS column)
__global__ __launch_bounds__(256) void k_gramgather(const float* __restrict__ Dict,
                                                    const int* __restrict__ chosen,
                                                    const u16* __restrict__ C0h,
                                                    float* __restrict__ GR,
                                                    float* __restrict__ Bm, int iter) {
    int t = threadIdx.x;
    int c = chosen[iter];
    if (blockIdx.x < MDIC) {
        int m = blockIdx.x;
        float4 a = ((const float4*)(Dict + (size_t)c * DIMK))[t];
        float4 b = ((const float4*)(Dict + (size_t)m * DIMK))[t];
        float s = a.x * b.x + a.y * b.y + a.z * b.z + a.w * b.w;
        s = blockReduce256f(s);
        if (t == 0) GR[(size_t)iter * MDIC + m] = s;
    } else {
        int n = (blockIdx.x - MDIC) * 256 + t;
        Bm[(size_t)iter * NROWS + n] = bf2f(C0h[(size_t)n * MDIC + c]);
    }
}

// build G_cc from GR gathers, Cholesky (serial, tiny), gather mdot
__global__ __launch_bounds__(256) void k_chol(const float* __restrict__ GR,
                                              const float* __restrict__ mdv,
                                              const int* __restrict__ chosen,
                                              float* __restrict__ Lmat,
                                              float* __restrict__ Gcc,
                                              float* __restrict__ mdot, int nat) {
    __shared__ float G[16][16];
    __shared__ float L[16][16];
    int t = threadIdx.x;
    if (t < nat * nat) {
        int a = t / nat, b = t % nat;
        G[a][b] = GR[(size_t)a * MDIC + chosen[b]];
    }
    if (t < nat) mdot[t] = mdv[chosen[t]];
    __syncthreads();
    if (t == 0) {
        for (int a = 0; a < nat; ++a)
            for (int b = 0; b <= a; ++b) {
                float s = G[a][b];
                for (int x = 0; x < b; ++x) s -= L[a][x] * L[b][x];
                L[a][b] = (a == b) ? sqrtf(fmaxf(s, 1e-20f)) : s / L[b][b];
            }
    }
    __syncthreads();
    if (t < nat * nat) {
        int a = t / nat, b = t % nat;
        Gcc[a * 16 + b]  = G[a][b];
        Lmat[a * 16 + b] = (b <= a) ? L[a][b] : 0.f;
    }
}

// fused per-row Cholesky solve + metric partials
template <int NAT>
__global__ __launch_bounds__(256) void k_solvestats(const float* __restrict__ Bm,
                                                    const float* __restrict__ Lmat,
                                                    const float* __restrict__ Gcc,
                                                    const float* __restrict__ mdot,
                                                    const float* __restrict__ Xnorm2,
                                                    const float* __restrict__ XdotM,
                                                    const double* __restrict__ scal,
                                                    float* __restrict__ Wm,
                                                    double* __restrict__ statsP) {
    __shared__ float L[16][16];
    __shared__ float G[16][16];
    __shared__ float mdl[16];
    int t = threadIdx.x;
    if (t < NAT * NAT) {
        L[t / NAT][t % NAT] = Lmat[(t / NAT) * 16 + (t % NAT)];
        G[t / NAT][t % NAT] = Gcc[(t / NAT) * 16 + (t % NAT)];
    }
    if (t < NAT) mdl[t] = mdot[t];
    __syncthreads();
    int n = blockIdx.x * 256 + t;
    float b[NAT], y[NAT], w[NAT];
    #pragma unroll
    for (int j = 0; j < NAT; ++j) b[j] = Bm[(size_t)j * NROWS + n];
    #pragma unroll
    for (int a = 0; a < NAT; ++a) {
        float s = b[a];
        #pragma unroll
        for (int x = 0; x < NAT; ++x) if (x < a) s -= L[a][x] * y[x];
        y[a] = s / L[a][a];
    }
    #pragma unroll
    for (int a = NAT - 1; a >= 0; --a) {
        float s = y[a];
        #pragma unroll
        for (int x = 0; x < NAT; ++x) if (x > a) s -= L[x][a] * w[x];
        w[a] = s / L[a][a];
    }
    #pragma unroll
    for (int j = 0; j < NAT; ++j) Wm[(size_t)j * NROWS + n] = w[j];

    float q = 0.f, wb = 0.f, wmd = 0.f, num1 = 0.f;
    #pragma unroll
    for (int j = 0; j < NAT; ++j) {
        float gw = 0.f;
        #pragma unroll
        for (int x = 0; x < NAT; ++x) gw += G[j][x] * w[x];
        q    += w[j] * gw;
        wb   += w[j] * b[j];
        wmd  += w[j] * mdl[j];
        num1 += w[j] * (b[j] + mdl[j]);
    }
    float xmn2 = (float)scal[2];
    float rec2 = xmn2 + 2.f * wmd + q;
    float na = fmaxf(sqrtf(Xnorm2[n]), 1e-8f);
    float nb = fmaxf(sqrtf(fmaxf(rec2, 0.f)), 1e-8f);
    float cosn = (XdotM[n] + num1) / (na * nb);

    double r0 = blockReduceD((double)q);
    double r1 = blockReduceD((double)wb);
    double r2 = blockReduceD((double)cosn);
    if (t == 0) {
        statsP[(size_t)blockIdx.x * 40 + 0] = r0;
        statsP[(size_t)blockIdx.x * 40 + 1] = r1;
        statsP[(size_t)blockIdx.x * 40 + 2] = r2;
    }
    for (int j = 0; j < NAT; ++j) {
        double rw = blockReduceD((double)w[j]);
        double rq = blockReduceD((double)w[j] * (double)w[j]);
        if (t == 0) {
            statsP[(size_t)blockIdx.x * 40 + 3 + j]  = rw;
            statsP[(size_t)blockIdx.x * 40 + 19 + j] = rq;
        }
    }
}

// single wave: combine 64 block partials -> evr/l2/cos (+weights on last iter)
template <int NAT>
__global__ __launch_bounds__(64) void k_finalize(const double* __restrict__ statsP,
                                                 const float* __restrict__ Gcc,
                                                 const double* __restrict__ scal,
                                                 float* __restrict__ out, int iter) {
    int t = threadIdx.x;
    double q  = statsP[(size_t)t * 40 + 0];
    double wb = statsP[(size_t)t * 40 + 1];
    double cs = statsP[(size_t)t * 40 + 2];
    double ws[NAT], wq[NAT];
    #pragma unroll
    for (int j = 0; j < NAT; ++j) {
        ws[j] = statsP[(size_t)t * 40 + 3 + j];
        wq[j] = statsP[(size_t)t * 40 + 19 + j];
    }
    #pragma unroll
    for (int off = 32; off > 0; off >>= 1) {
        q  += __shfl_down(q, off);
        wb += __shfl_down(wb, off);
        cs += __shfl_down(cs, off);
        #pragma unroll
        for (int j = 0; j < NAT; ++j) {
            ws[j] += __shfl_down(ws[j], off);
            wq[j] += __shfl_down(wq[j], off);
        }
    }
    double wbar[NAT];
    #pragma unroll
    for (int j = 0; j < NAT; ++j) wbar[j] = __shfl(ws[j], 0) / (double)NROWS;
    double wg = 0.0;
    for (int idx = t; idx < NAT * NAT; idx += 64) {
        int a = idx / NAT, b = idx % NAT;
        wg += wbar[a] * wbar[b] * (double)Gcc[a * 16 + b];
    }
    #pragma unroll
    for (int off = 32; off > 0; off >>= 1) wg += __shfl_down(wg, off);
    if (t == 0) {
        double sumXc2 = scal[1];
        out[OFF_EVR + iter] = (float)((q - (double)NROWS * wg) / sumXc2);
        out[OFF_L2  + iter] = (float)((sumXc2 - 2.0 * wb + q) / ((double)NROWS * (double)DIMK));
        out[OFF_COS + iter] = (float)(cs / (double)NROWS);
        if (NAT == KSEL) {
            for (int j = 0; j < NAT; ++j)
                out[OFF_WEIGHTS + j] = (float)sqrt(wq[j]);
        }
    }
}

// final recon / residual outputs
__global__ __launch_bounds__(256) void k_outfinal(const float* __restrict__ X,
                                                  const float* __restrict__ xmean,
                                                  const float* __restrict__ Dict,
                                                  const int* __restrict__ chosen,
                                                  const float* __restrict__ Wm,
                                                  float* __restrict__ out) {
    __shared__ int cI[16];
    int t = threadIdx.x;
    if (t < 16) cI[t] = chosen[t];
    __syncthreads();
    int n0 = blockIdx.x * 8;
    float4 xm = ((const float4*)xmean)[t];
    for (int r = 0; r < 8; ++r) {
        int n = n0 + r;
        float w[16];
        #pragma unroll
        for (int j = 0; j < 16; ++j) w[j] = Wm[(size_t)j * NROWS + n];
        float4 rec = xm;
        #pragma unroll
        for (int j = 0; j < 16; ++j) {
            float4 a = ((const float4*)(Dict + (size_t)cI[j] * DIMK))[t];
            rec.x += w[j] * a.x; rec.y += w[j] * a.y;
            rec.z += w[j] * a.z; rec.w += w[j] * a.w;
        }
        float4 xv = ((const float4*)(X + (size_t)n * DIMK))[t];
        float4 res = {xv.x - rec.x, xv.y - rec.y, xv.z - rec.z, xv.w - rec.w};
        ((float4*)(out + OFF_RECON + (size_t)n * DIMK))[t] = rec;
        ((float4*)(out + OFF_RESID + (size_t)n * DIMK))[t] = res;
    }
}

__global__ __launch_bounds__(256) void k_wt(const float* __restrict__ Wm,
                                            float* __restrict__ out) {
    int idx = blockIdx.x * 256 + threadIdx.x;  // n*16 + j
    int n = idx >> 4, j = idx & 15;
    out[OFF_WT + idx] = Wm[(size_t)j * NROWS + n];
}

// ------------------------------ host side ------------------------------------
struct IterArgs {
    const float *X, *Dict;
    u16 *C0h;
    float *GR, *W, *Bm, *md, *xmean, *Xnorm2, *XdotM, *notchosen, *Lmat, *Gcc, *mdot;
    float *scorePf;
    u64 *amx;
    double *scal, *statsP;
    int *chosen;
    float *out;
    hipStream_t stream;
};

template <int I>
static void run_iter(const IterArgs& a) {
    k_score<I><<<dim3(4, 256), 256, 0, a.stream>>>(a.C0h, a.GR, a.W, a.scorePf);
    k_scoreargmax<<<16, 256, 0, a.stream>>>(a.scorePf, a.notchosen, a.amx, a.chosen,
                                            a.out + OFF_CHOSEN, I);
    k_gramgather<<<MDIC + 64, 256, 0, a.stream>>>(a.Dict, a.chosen, a.C0h, a.GR, a.Bm, I);
    k_chol<<<1, 256, 0, a.stream>>>(a.GR, a.md, a.chosen, a.Lmat, a.Gcc, a.mdot, I + 1);
    k_solvestats<I + 1><<<64, 256, 0, a.stream>>>(a.Bm, a.Lmat, a.Gcc, a.mdot,
                                                  a.Xnorm2, a.XdotM, a.scal, a.W, a.statsP);
    k_finalize<I + 1><<<1, 64, 0, a.stream>>>(a.statsP, a.Gcc, a.scal, a.out, I);
}

template <int I>
struct Loop {
    static void go(const IterArgs& a) { run_iter<I>(a); Loop<I + 1>::go(a); }
};
template <>
struct Loop<KSEL> { static void go(const IterArgs&) {} };

extern "C" void kernel_launch(void* const* d_in, const int* in_sizes, int n_in,
                              void* d_out, int out_size, void* d_ws, size_t ws_size,
                              hipStream_t stream) {
    (void)in_sizes; (void)n_in; (void)out_size;
    const float* X    = (const float*)d_in[0];
    const float* Dict = (const float*)d_in[1];
    float* out = (float*)d_out;

    char* ws = (char*)d_ws;
    size_t off = 0;
    auto carve = [&](size_t bytes) -> char* {
        char* p = ws + off;
        off += (bytes + 255) & ~(size_t)255;
        return p;
    };
    u16*    C0h       = (u16*)   carve((size_t)NROWS * MDIC * 2);   // 134 MB
    float*  GR        = (float*) carve((size_t)KSEL * MDIC * 4);
    float*  W         = (float*) carve((size_t)KSEL * NROWS * 4);
    float*  Bm        = (float*) carve((size_t)KSEL * NROWS * 4);
    float*  md        = (float*) carve((size_t)MDIC * 4);
    float*  xmean     = (float*) carve((size_t)DIMK * 4);
    float*  colpart   = (float*) carve((size_t)64 * DIMK * 4);
    float*  sqpart    = (float*) carve(256 * 4);
    float*  Xnorm2    = (float*) carve((size_t)NROWS * 4);
    float*  XdotM     = (float*) carve((size_t)NROWS * 4);
    float*  scorePf   = (float*) carve((size_t)256 * MDIC * 4);     // 4 MB
    float*  notchosen = (float*) carve((size_t)MDIC * 4);
    u64*    amx       = (u64*)   carve(2 * 8);
    int*    chosen    = (int*)   carve(KSEL * 4);
    float*  Lmat      = (float*) carve(256 * 4);
    float*  Gcc       = (float*) carve(256 * 4);
    float*  mdot      = (float*) carve(16 * 4);
    double* scal      = (double*)carve(8 * 8);
    double* statsP    = (double*)carve((size_t)64 * 40 * 8);
    u16*    Bhi       = (u16*)   carve((size_t)MDIC * DIMK * 2);    // 8 MB
    u16*    Blo       = (u16*)   carve((size_t)MDIC * DIMK * 2);    // 8 MB

    // A-plane chunk buffers take the tail of ws; pick largest chunk that fits.
    int chunkrows = 0;
    for (int cr = NROWS; cr >= 128; cr >>= 1) {
        size_t need = (size_t)cr * DIMK * 2 * 2 + 512;
        if (off + need <= ws_size) { chunkrows = cr; break; }
    }
    if (chunkrows == 0) chunkrows = 128;
    u16* Ahi = (u16*) carve((size_t)chunkrows * DIMK * 2);
    u16* Alo = (u16*) carve((size_t)chunkrows * DIMK * 2);

    k_init<<<MDIC / 256, 256, 0, stream>>>(notchosen, amx);
    k_colstats<<<dim3(4, 64), 256, 0, stream>>>(X, colpart, sqpart);
    k_reduce_mean<<<1, 1024, 0, stream>>>(colpart, sqpart, xmean, scal);
    k_md<<<MDIC, 256, 0, stream>>>(Dict, xmean, md);
    k_rowstats<<<NROWS, 256, 0, stream>>>(X, xmean, Xnorm2, XdotM);

    // bf16 hi/lo planes + chunked MFMA GEMM
    k_split<<<(MDIC * DIMK) / 1024, 256, 0, stream>>>(Dict, Bhi, Blo);
    int nchunks = NROWS / chunkrows;
    for (int c = 0; c < nchunks; ++c) {
        k_split<<<(chunkrows * DIMK) / 1024, 256, 0, stream>>>(
            X + (size_t)c * chunkrows * DIMK, Ahi, Alo);
        k_gemm_mfma<<<dim3(MDIC / 128, chunkrows / 128), 256, 0, stream>>>(
            Ahi, Alo, Bhi, Blo, md, C0h, c * chunkrows);
    }

    IterArgs a{X, Dict, C0h, GR, W, Bm, md, xmean, Xnorm2, XdotM, notchosen,
               Lmat, Gcc, mdot, scorePf, amx, scal, statsP, chosen, out, stream};
    Loop<0>::go(a);

    k_outfinal<<<NROWS / 8, 256, 0, stream>>>(X, xmean, Dict, chosen, W, out);
    k_wt<<<NROWS * KSEL / 256, 256, 0, stream>>>(W, out);
}